// Round 1
// baseline (610.194 us; speedup 1.0000x reference)
//
#include <hip/hip_runtime.h>
#include <stdint.h>

#define NN 100000
#define NE 1600000

using u16 = unsigned short;
using u32 = unsigned int;

typedef __attribute__((ext_vector_type(8))) short bf16x8;
typedef __attribute__((ext_vector_type(4))) float f32x4;

__device__ inline u16 f2b(float f){
  u32 u = __float_as_uint(f);
  u32 r = (u + 0x7fffu + ((u >> 16) & 1u)) >> 16;
  return (u16)r;
}

// ---------------- weight prep: fp32 -> bf16, transposed [n][k] ----------------
__global__ void k_prep(const float* __restrict__ Wp1, const float* __restrict__ Ws1,
                       const float* __restrict__ Wn1, const float* __restrict__ Wp2,
                       const float* __restrict__ Ws2, const float* __restrict__ Wn2,
                       u16* __restrict__ wpT1, u16* __restrict__ wc1T,
                       u16* __restrict__ wpT2, u16* __restrict__ wc2T){
  int i = blockIdx.x * 256 + threadIdx.x;
  if (i < 16384){ int n = i >> 7, k = i & 127;
    wpT1[n*128 + k] = f2b(Wp1[k*128 + n]);
    wpT2[n*128 + k] = f2b(Wp2[k*128 + n]);
  }
  if (i < 32768){ int n = i >> 8, k = i & 255;
    float v = (k < 128) ? Ws1[k*128 + n] : Wn1[(k-128)*128 + n];
    wc1T[n*256 + k] = f2b(v);
  }
  if (i < 12288){ int n = i >> 8, k = i & 255;
    float v = 0.f;
    if (n < 40) v = (k < 128) ? Ws2[k*40 + n] : Wn2[(k-128)*40 + n];
    wc2T[n*256 + k] = f2b(v);
  }
}

// ---------------- CSR build ----------------
__global__ void k_hist(const int* __restrict__ dst, int* __restrict__ deg){
  int e = blockIdx.x * 256 + threadIdx.x;
  if (e < NE) atomicAdd(&deg[dst[e]], 1);
}

__global__ void k_bsum(const int* __restrict__ deg, int* __restrict__ bsum){
  __shared__ int sd[1024];
  int i = blockIdx.x * 1024 + threadIdx.x;
  sd[threadIdx.x] = (i < NN) ? deg[i] : 0;
  __syncthreads();
  for (int s = 512; s > 0; s >>= 1){
    if (threadIdx.x < s) sd[threadIdx.x] += sd[threadIdx.x + s];
    __syncthreads();
  }
  if (threadIdx.x == 0) bsum[blockIdx.x] = sd[0];
}

__global__ void k_scan_bsum(int* __restrict__ bsum, int nb){
  if (threadIdx.x == 0 && blockIdx.x == 0){
    int a = 0;
    for (int i = 0; i < nb; i++){ int t = bsum[i]; bsum[i] = a; a += t; }
  }
}

__global__ void k_scan(int* __restrict__ deg, const int* __restrict__ bsum,
                       int* __restrict__ rp){
  __shared__ int sd[1024];
  int i = blockIdx.x * 1024 + threadIdx.x;
  int v = (i < NN) ? deg[i] : 0;
  sd[threadIdx.x] = v;
  __syncthreads();
  for (int off = 1; off < 1024; off <<= 1){
    int t = (threadIdx.x >= off) ? sd[threadIdx.x - off] : 0;
    __syncthreads();
    sd[threadIdx.x] += t;
    __syncthreads();
  }
  int ex = bsum[blockIdx.x] + sd[threadIdx.x] - v;  // exclusive
  if (i < NN){ rp[i] = ex; deg[i] = ex; }           // deg becomes fill cursor
  if (i == NN - 1) rp[NN] = ex + v;
}

__global__ void k_fill(const int* __restrict__ src, const int* __restrict__ dst,
                       int* __restrict__ cur, int* __restrict__ esrc){
  int e = blockIdx.x * 256 + threadIdx.x;
  if (e < NE){
    int p = atomicAdd(&cur[dst[e]], 1);
    esrc[p] = src[e];
  }
}

// ---------------- segment-max aggregation (one wave per node) ----------------
// messages are post-ReLU (>=0), so init 0 reproduces where(isfinite(max), max, 0)
__global__ void k_agg(const u16* __restrict__ hp, const int* __restrict__ rp,
                      const int* __restrict__ esrc, u16* __restrict__ agg){
  int node = blockIdx.x * 4 + (threadIdx.x >> 6);
  if (node >= NN) return;
  int lane = threadIdx.x & 63;
  int lo = rp[node], hi = rp[node + 1];
  float m0 = 0.f, m1 = 0.f;
  for (int i = lo; i < hi; i++){
    int s = esrc[i];
    u32 v = *(const u32*)&hp[(size_t)s * 128 + lane * 2];
    m0 = fmaxf(m0, __uint_as_float(v << 16));
    m1 = fmaxf(m1, __uint_as_float(v & 0xffff0000u));
  }
  u32 o = (u32)f2b(m0) | ((u32)f2b(m1) << 16);
  *(u32*)&agg[(size_t)node * 128 + lane * 2] = o;
}

// ---------------- bf16 MFMA GEMM: out = [A1|A2] @ Wt^T + bias (opt relu) -----
// Wt is pre-transposed bf16 [NOUT][K]. A rows are [N][128] (f32 or bf16).
// 16x16x32 MFMA; lane frag A: row=l&15, k=(l>>4)*8+i ; B: k=(l>>4)*8+i, col=l&15
// C/D: col=l&15, row=(l>>4)*4+reg  (m89-verified).
template<int K, int NOUT, int NOUTR, int BM, int NT,
         bool A1F32, bool HASA2, bool RELU, bool OUTF32>
__global__ __launch_bounds__(NT)
void k_gemm(const void* __restrict__ A1p, const u16* __restrict__ A2,
            const u16* __restrict__ Wt, const float* __restrict__ bias,
            void* __restrict__ outp)
{
  constexpr int KSTEP = 64;
  constexpr int KP = KSTEP + 8;     // 72 elems = 144 B rows (16B-aligned, 2-way banks)
  constexpr int NTI = NOUT / 16;
  __shared__ u16 A_lds[BM * KP];
  __shared__ u16 W_lds[NOUT * KP];
  const int tid  = threadIdx.x;
  const int row0 = blockIdx.x * BM;
  const int wave = tid >> 6, lane = tid & 63;
  const int koff = (lane >> 4) * 8;
  const u16* Ar = &A_lds[(wave * 16 + (lane & 15)) * KP];

  f32x4 acc[NTI] = {};

  #pragma unroll
  for (int k0 = 0; k0 < K; k0 += KSTEP){
    if (k0) __syncthreads();
    // stage W chunk [NOUT][64]
    for (int c = tid; c < NOUT * 8; c += NT){
      int n = c >> 3, kc = c & 7;
      *(uint4*)&W_lds[n * KP + kc * 8] = *(const uint4*)&Wt[n * K + k0 + kc * 8];
    }
    // stage A chunk [BM][64]
    if (A1F32 && k0 < 128){
      const float* A = (const float*)A1p;
      for (int c = tid; c < BM * 16; c += NT){
        int rl = c >> 4, kc = c & 15;
        int gr = row0 + rl;
        float4 v = make_float4(0.f, 0.f, 0.f, 0.f);
        if (gr < NN) v = *(const float4*)&A[(size_t)gr * 128 + k0 + kc * 4];
        ushort4 o; o.x = f2b(v.x); o.y = f2b(v.y); o.z = f2b(v.z); o.w = f2b(v.w);
        *(ushort4*)&A_lds[rl * KP + kc * 4] = o;
      }
    } else {
      const u16* A = (HASA2 && k0 >= 128) ? A2 : (const u16*)A1p;
      int cb = (HASA2 && k0 >= 128) ? (k0 - 128) : k0;
      for (int c = tid; c < BM * 8; c += NT){
        int rl = c >> 3, kc = c & 7;
        int gr = row0 + rl;
        uint4 v = make_uint4(0, 0, 0, 0);
        if (gr < NN) v = *(const uint4*)&A[(size_t)gr * 128 + cb + kc * 8];
        *(uint4*)&A_lds[rl * KP + kc * 8] = v;
      }
    }
    __syncthreads();

    bf16x8 af0 = *(const bf16x8*)&Ar[koff];
    bf16x8 af1 = *(const bf16x8*)&Ar[32 + koff];
    #pragma unroll
    for (int nt = 0; nt < NTI; nt++){
      const u16* Wr = &W_lds[(nt * 16 + (lane & 15)) * KP];
      bf16x8 b0 = *(const bf16x8*)&Wr[koff];
      bf16x8 b1 = *(const bf16x8*)&Wr[32 + koff];
      acc[nt] = __builtin_amdgcn_mfma_f32_16x16x32_bf16(af0, b0, acc[nt], 0, 0, 0);
      acc[nt] = __builtin_amdgcn_mfma_f32_16x16x32_bf16(af1, b1, acc[nt], 0, 0, 0);
    }
  }

  const int colb = lane & 15;
  const int rowl = wave * 16 + ((lane >> 4) << 2);
  #pragma unroll
  for (int nt = 0; nt < NTI; nt++){
    int col = nt * 16 + colb;
    if (col >= NOUTR) continue;
    float bv = bias[col];
    #pragma unroll
    for (int r = 0; r < 4; r++){
      int gr = row0 + rowl + r;
      if (gr >= NN) continue;
      float v = acc[nt][r] + bv;
      if (RELU) v = fmaxf(v, 0.f);
      if (OUTF32) ((float*)outp)[(size_t)gr * NOUTR + col] = v;
      else        ((u16*)outp)[(size_t)gr * NOUTR + col] = f2b(v);
    }
  }
}

// ---------------- host launch ----------------
extern "C" void kernel_launch(void* const* d_in, const int* in_sizes, int n_in,
                              void* d_out, int out_size, void* d_ws, size_t ws_size,
                              hipStream_t stream){
  const float* x   = (const float*)d_in[0];
  const int*   src = (const int*)d_in[1];
  const int*   dst = (const int*)d_in[2];
  const float* Wp1 = (const float*)d_in[3];
  const float* bp1 = (const float*)d_in[4];
  const float* Ws1 = (const float*)d_in[5];
  const float* Wn1 = (const float*)d_in[6];
  const float* b1  = (const float*)d_in[7];
  const float* Wp2 = (const float*)d_in[8];
  const float* bp2 = (const float*)d_in[9];
  const float* Ws2 = (const float*)d_in[10];
  const float* Wn2 = (const float*)d_in[11];
  const float* b2  = (const float*)d_in[12];

  char* ws = (char*)d_ws;
  u16* wpT1 = (u16*)(ws + 0);            // 128x128 bf16
  u16* wc1T = (u16*)(ws + 32768);        // 128x256 bf16
  u16* wpT2 = (u16*)(ws + 98304);        // 128x128 bf16
  u16* wc2T = (u16*)(ws + 131072);       // 48x256 bf16 (cols 40..47 zero)
  int* rp   = (int*)(ws + 155648);       // N+1
  int* degc = (int*)(ws + 555776);       // N (deg, then fill cursor)
  int* bsum = (int*)(ws + 955776);       // 128
  int* esrc = (int*)(ws + 956288);       // E (src ids bucketed by dst)
  u16* hp   = (u16*)(ws + 7356416);      // N x 128 bf16
  u16* agg  = (u16*)(ws + 32956416);     // N x 128 bf16
  u16* h    = (u16*)(ws + 58556416);     // N x 128 bf16

  hipMemsetAsync(degc, 0, NN * sizeof(int), stream);
  k_prep<<<128, 256, 0, stream>>>(Wp1, Ws1, Wn1, Wp2, Ws2, Wn2, wpT1, wc1T, wpT2, wc2T);
  k_hist<<<(NE + 255) / 256, 256, 0, stream>>>(dst, degc);
  k_bsum<<<98, 1024, 0, stream>>>(degc, bsum);
  k_scan_bsum<<<1, 64, 0, stream>>>(bsum, 98);
  k_scan<<<98, 1024, 0, stream>>>(degc, bsum, rp);
  k_fill<<<(NE + 255) / 256, 256, 0, stream>>>(src, dst, degc, esrc);

  // layer 1
  k_gemm<128,128,128, 64,256, true ,false,true ,false>
      <<<(NN + 63) / 64, 256, 0, stream>>>(x, nullptr, wpT1, bp1, hp);
  k_agg<<<(NN + 3) / 4, 256, 0, stream>>>(hp, rp, esrc, agg);
  k_gemm<256,128,128,128,512, true ,true ,true ,false>
      <<<(NN + 127) / 128, 512, 0, stream>>>(x, agg, wc1T, b1, h);
  // layer 2
  k_gemm<128,128,128, 64,256, false,false,true ,false>
      <<<(NN + 63) / 64, 256, 0, stream>>>(h, nullptr, wpT2, bp2, hp);
  k_agg<<<(NN + 3) / 4, 256, 0, stream>>>(hp, rp, esrc, agg);
  k_gemm<256, 48, 40,128,512, false,true ,false,true >
      <<<(NN + 127) / 128, 512, 0, stream>>>(h, agg, wc2T, b2, d_out);
}

// Round 2
// 425.805 us; speedup vs baseline: 1.4330x; 1.4330x over previous
//
#include <hip/hip_runtime.h>
#include <stdint.h>

#define NN 100000
#define NE 1600000

using u16 = unsigned short;
using u32 = unsigned int;

typedef __attribute__((ext_vector_type(8))) short bf16x8;
typedef __attribute__((ext_vector_type(4))) float f32x4;

__device__ inline u16 f2b(float f){
  u32 u = __float_as_uint(f);
  u32 r = (u + 0x7fffu + ((u >> 16) & 1u)) >> 16;
  return (u16)r;
}

// ---------------- weight prep: fp32 -> bf16, transposed [n][k] ----------------
__global__ void k_prep(const float* __restrict__ Wp1, const float* __restrict__ Ws1,
                       const float* __restrict__ Wn1, const float* __restrict__ Wp2,
                       const float* __restrict__ Ws2, const float* __restrict__ Wn2,
                       u16* __restrict__ wpT1, u16* __restrict__ wc1T,
                       u16* __restrict__ wpT2, u16* __restrict__ wc2T){
  int i = blockIdx.x * 256 + threadIdx.x;
  if (i < 16384){ int n = i >> 7, k = i & 127;
    wpT1[n*128 + k] = f2b(Wp1[k*128 + n]);
    wpT2[n*128 + k] = f2b(Wp2[k*128 + n]);
  }
  if (i < 32768){ int n = i >> 8, k = i & 255;
    float v = (k < 128) ? Ws1[k*128 + n] : Wn1[(k-128)*128 + n];
    wc1T[n*256 + k] = f2b(v);
  }
  if (i < 12288){ int n = i >> 8, k = i & 255;
    float v = 0.f;
    if (n < 40) v = (k < 128) ? Ws2[k*40 + n] : Wn2[(k-128)*40 + n];
    wc2T[n*256 + k] = f2b(v);
  }
}

// ---------------- CSR build ----------------
__global__ void k_hist(const int* __restrict__ dst, int* __restrict__ deg){
  int e = blockIdx.x * 256 + threadIdx.x;
  if (e < NE) atomicAdd(&deg[dst[e]], 1);
}

__global__ void k_bsum(const int* __restrict__ deg, int* __restrict__ bsum){
  __shared__ int sd[1024];
  int i = blockIdx.x * 1024 + threadIdx.x;
  sd[threadIdx.x] = (i < NN) ? deg[i] : 0;
  __syncthreads();
  for (int s = 512; s > 0; s >>= 1){
    if (threadIdx.x < s) sd[threadIdx.x] += sd[threadIdx.x + s];
    __syncthreads();
  }
  if (threadIdx.x == 0) bsum[blockIdx.x] = sd[0];
}

__global__ void k_scan_bsum(int* __restrict__ bsum, int nb){
  if (threadIdx.x == 0 && blockIdx.x == 0){
    int a = 0;
    for (int i = 0; i < nb; i++){ int t = bsum[i]; bsum[i] = a; a += t; }
  }
}

__global__ void k_scan(int* __restrict__ deg, const int* __restrict__ bsum,
                       int* __restrict__ rp){
  __shared__ int sd[1024];
  int i = blockIdx.x * 1024 + threadIdx.x;
  int v = (i < NN) ? deg[i] : 0;
  sd[threadIdx.x] = v;
  __syncthreads();
  for (int off = 1; off < 1024; off <<= 1){
    int t = (threadIdx.x >= off) ? sd[threadIdx.x - off] : 0;
    __syncthreads();
    sd[threadIdx.x] += t;
    __syncthreads();
  }
  int ex = bsum[blockIdx.x] + sd[threadIdx.x] - v;  // exclusive
  if (i < NN){ rp[i] = ex; deg[i] = ex; }           // deg becomes fill cursor
  if (i == NN - 1) rp[NN] = ex + v;
}

__global__ void k_fill(const int* __restrict__ src, const int* __restrict__ dst,
                       int* __restrict__ cur, int* __restrict__ esrc){
  int e = blockIdx.x * 256 + threadIdx.x;
  if (e < NE){
    int p = atomicAdd(&cur[dst[e]], 1);
    esrc[p] = src[e];
  }
}

// ---------------- segment-max aggregation (one wave per node) ----------------
// messages are post-ReLU (>=0), so init 0 reproduces where(isfinite(max), max, 0).
// Unroll x8 with batched loads: 8 index loads then 8 independent row-gathers in
// flight -> dependent-chain depth drops from deg to ~deg/8. Tail slots clamp to
// hi-1 (duplicate rows are harmless under max with m>=0) -> no masking.
__global__ void k_agg(const u16* __restrict__ hp, const int* __restrict__ rp,
                      const int* __restrict__ esrc, u16* __restrict__ agg){
  int node = blockIdx.x * 4 + (threadIdx.x >> 6);
  if (node >= NN) return;
  int lane = threadIdx.x & 63;
  int lo = rp[node], hi = rp[node + 1];
  float m0 = 0.f, m1 = 0.f;
  for (int i = lo; i < hi; i += 8){
    int s[8];
    #pragma unroll
    for (int j = 0; j < 8; j++){
      int ii = i + j; if (ii >= hi) ii = hi - 1;
      s[j] = esrc[ii];
    }
    u32 v[8];
    #pragma unroll
    for (int j = 0; j < 8; j++)
      v[j] = *(const u32*)&hp[(size_t)s[j] * 128 + lane * 2];
    #pragma unroll
    for (int j = 0; j < 8; j++){
      m0 = fmaxf(m0, __uint_as_float(v[j] << 16));
      m1 = fmaxf(m1, __uint_as_float(v[j] & 0xffff0000u));
    }
  }
  u32 o = (u32)f2b(m0) | ((u32)f2b(m1) << 16);
  *(u32*)&agg[(size_t)node * 128 + lane * 2] = o;
}

// ---------------- bf16 MFMA GEMM: out = [A1|A2] @ Wt^T + bias (opt relu) -----
// Wt is pre-transposed bf16 [NOUT][K]. A rows are [N][128] (f32 or bf16).
// 16x16x32 MFMA; lane frag A: row=l&15, k=(l>>4)*8+i ; B: k=(l>>4)*8+i, col=l&15
// C/D: col=l&15, row=(l>>4)*4+reg  (m89-verified).
template<int K, int NOUT, int NOUTR, int BM, int NT,
         bool A1F32, bool HASA2, bool RELU, bool OUTF32>
__global__ __launch_bounds__(NT)
void k_gemm(const void* __restrict__ A1p, const u16* __restrict__ A2,
            const u16* __restrict__ Wt, const float* __restrict__ bias,
            void* __restrict__ outp)
{
  constexpr int KSTEP = 64;
  constexpr int KP = KSTEP + 8;     // 72 elems = 144 B rows (16B-aligned, 2-way banks)
  constexpr int NTI = NOUT / 16;
  __shared__ u16 A_lds[BM * KP];
  __shared__ u16 W_lds[NOUT * KP];
  const int tid  = threadIdx.x;
  const int row0 = blockIdx.x * BM;
  const int wave = tid >> 6, lane = tid & 63;
  const int koff = (lane >> 4) * 8;
  const u16* Ar = &A_lds[(wave * 16 + (lane & 15)) * KP];

  f32x4 acc[NTI] = {};

  #pragma unroll
  for (int k0 = 0; k0 < K; k0 += KSTEP){
    if (k0) __syncthreads();
    // stage W chunk [NOUT][64]
    for (int c = tid; c < NOUT * 8; c += NT){
      int n = c >> 3, kc = c & 7;
      *(uint4*)&W_lds[n * KP + kc * 8] = *(const uint4*)&Wt[n * K + k0 + kc * 8];
    }
    // stage A chunk [BM][64]
    if (A1F32 && k0 < 128){
      const float* A = (const float*)A1p;
      for (int c = tid; c < BM * 16; c += NT){
        int rl = c >> 4, kc = c & 15;
        int gr = row0 + rl;
        float4 v = make_float4(0.f, 0.f, 0.f, 0.f);
        if (gr < NN) v = *(const float4*)&A[(size_t)gr * 128 + k0 + kc * 4];
        ushort4 o; o.x = f2b(v.x); o.y = f2b(v.y); o.z = f2b(v.z); o.w = f2b(v.w);
        *(ushort4*)&A_lds[rl * KP + kc * 4] = o;
      }
    } else {
      const u16* A = (HASA2 && k0 >= 128) ? A2 : (const u16*)A1p;
      int cb = (HASA2 && k0 >= 128) ? (k0 - 128) : k0;
      for (int c = tid; c < BM * 8; c += NT){
        int rl = c >> 3, kc = c & 7;
        int gr = row0 + rl;
        uint4 v = make_uint4(0, 0, 0, 0);
        if (gr < NN) v = *(const uint4*)&A[(size_t)gr * 128 + cb + kc * 8];
        *(uint4*)&A_lds[rl * KP + kc * 8] = v;
      }
    }
    __syncthreads();

    bf16x8 af0 = *(const bf16x8*)&Ar[koff];
    bf16x8 af1 = *(const bf16x8*)&Ar[32 + koff];
    #pragma unroll
    for (int nt = 0; nt < NTI; nt++){
      const u16* Wr = &W_lds[(nt * 16 + (lane & 15)) * KP];
      bf16x8 b0 = *(const bf16x8*)&Wr[koff];
      bf16x8 b1 = *(const bf16x8*)&Wr[32 + koff];
      acc[nt] = __builtin_amdgcn_mfma_f32_16x16x32_bf16(af0, b0, acc[nt], 0, 0, 0);
      acc[nt] = __builtin_amdgcn_mfma_f32_16x16x32_bf16(af1, b1, acc[nt], 0, 0, 0);
    }
  }

  const int colb = lane & 15;
  const int rowl = wave * 16 + ((lane >> 4) << 2);
  #pragma unroll
  for (int nt = 0; nt < NTI; nt++){
    int col = nt * 16 + colb;
    if (col >= NOUTR) continue;
    float bv = bias[col];
    #pragma unroll
    for (int r = 0; r < 4; r++){
      int gr = row0 + rowl + r;
      if (gr >= NN) continue;
      float v = acc[nt][r] + bv;
      if (RELU) v = fmaxf(v, 0.f);
      if (OUTF32) ((float*)outp)[(size_t)gr * NOUTR + col] = v;
      else        ((u16*)outp)[(size_t)gr * NOUTR + col] = f2b(v);
    }
  }
}

// ---------------- host launch ----------------
extern "C" void kernel_launch(void* const* d_in, const int* in_sizes, int n_in,
                              void* d_out, int out_size, void* d_ws, size_t ws_size,
                              hipStream_t stream){
  const float* x   = (const float*)d_in[0];
  const int*   src = (const int*)d_in[1];
  const int*   dst = (const int*)d_in[2];
  const float* Wp1 = (const float*)d_in[3];
  const float* bp1 = (const float*)d_in[4];
  const float* Ws1 = (const float*)d_in[5];
  const float* Wn1 = (const float*)d_in[6];
  const float* b1  = (const float*)d_in[7];
  const float* Wp2 = (const float*)d_in[8];
  const float* bp2 = (const float*)d_in[9];
  const float* Ws2 = (const float*)d_in[10];
  const float* Wn2 = (const float*)d_in[11];
  const float* b2  = (const float*)d_in[12];

  char* ws = (char*)d_ws;
  u16* wpT1 = (u16*)(ws + 0);            // 128x128 bf16
  u16* wc1T = (u16*)(ws + 32768);        // 128x256 bf16
  u16* wpT2 = (u16*)(ws + 98304);        // 128x128 bf16
  u16* wc2T = (u16*)(ws + 131072);       // 48x256 bf16 (cols 40..47 zero)
  int* rp   = (int*)(ws + 155648);       // N+1
  int* degc = (int*)(ws + 555776);       // N (deg, then fill cursor)
  int* bsum = (int*)(ws + 955776);       // 128
  int* esrc = (int*)(ws + 956288);       // E (src ids bucketed by dst)
  u16* hp   = (u16*)(ws + 7356416);      // N x 128 bf16
  u16* agg  = (u16*)(ws + 32956416);     // N x 128 bf16
  u16* h    = (u16*)(ws + 58556416);     // N x 128 bf16

  hipMemsetAsync(degc, 0, NN * sizeof(int), stream);
  k_prep<<<128, 256, 0, stream>>>(Wp1, Ws1, Wn1, Wp2, Ws2, Wn2, wpT1, wc1T, wpT2, wc2T);
  k_hist<<<(NE + 255) / 256, 256, 0, stream>>>(dst, degc);
  k_bsum<<<98, 1024, 0, stream>>>(degc, bsum);
  k_scan_bsum<<<1, 64, 0, stream>>>(bsum, 98);
  k_scan<<<98, 1024, 0, stream>>>(degc, bsum, rp);
  k_fill<<<(NE + 255) / 256, 256, 0, stream>>>(src, dst, degc, esrc);

  // layer 1
  k_gemm<128,128,128, 64,256, true ,false,true ,false>
      <<<(NN + 63) / 64, 256, 0, stream>>>(x, nullptr, wpT1, bp1, hp);
  k_agg<<<(NN + 3) / 4, 256, 0, stream>>>(hp, rp, esrc, agg);
  k_gemm<256,128,128,128,512, true ,true ,true ,false>
      <<<(NN + 127) / 128, 512, 0, stream>>>(x, agg, wc1T, b1, h);
  // layer 2
  k_gemm<128,128,128, 64,256, false,false,true ,false>
      <<<(NN + 63) / 64, 256, 0, stream>>>(h, nullptr, wpT2, bp2, hp);
  k_agg<<<(NN + 3) / 4, 256, 0, stream>>>(hp, rp, esrc, agg);
  k_gemm<256, 48, 40,128,512, false,true ,false,true >
      <<<(NN + 127) / 128, 512, 0, stream>>>(h, agg, wc2T, b2, d_out);
}

// Round 3
// 282.282 us; speedup vs baseline: 2.1616x; 1.5084x over previous
//
#include <hip/hip_runtime.h>
#include <stdint.h>

#define NN 100000
#define NE 1600000
#define NB 391          // coarse buckets of 256 nodes: bucket = dst >> 8

using u16 = unsigned short;
using u32 = unsigned int;

typedef __attribute__((ext_vector_type(8))) short bf16x8;
typedef __attribute__((ext_vector_type(4))) float f32x4;

__device__ inline u16 f2b(float f){
  u32 u = __float_as_uint(f);
  u32 r = (u + 0x7fffu + ((u >> 16) & 1u)) >> 16;
  return (u16)r;
}

// ---------------- weight prep: fp32 -> bf16, transposed [n][k] ----------------
__global__ void k_prep(const float* __restrict__ Wp1, const float* __restrict__ Ws1,
                       const float* __restrict__ Wn1, const float* __restrict__ Wp2,
                       const float* __restrict__ Ws2, const float* __restrict__ Wn2,
                       u16* __restrict__ wpT1, u16* __restrict__ wc1T,
                       u16* __restrict__ wpT2, u16* __restrict__ wc2T){
  int i = blockIdx.x * 256 + threadIdx.x;
  if (i < 16384){ int n = i >> 7, k = i & 127;
    wpT1[n*128 + k] = f2b(Wp1[k*128 + n]);
    wpT2[n*128 + k] = f2b(Wp2[k*128 + n]);
  }
  if (i < 32768){ int n = i >> 8, k = i & 255;
    float v = (k < 128) ? Ws1[k*128 + n] : Wn1[(k-128)*128 + n];
    wc1T[n*256 + k] = f2b(v);
  }
  if (i < 12288){ int n = i >> 8, k = i & 255;
    float v = 0.f;
    if (n < 40) v = (k < 128) ? Ws2[k*40 + n] : Wn2[(k-128)*40 + n];
    wc2T[n*256 + k] = f2b(v);
  }
}

// ---------------- CSR build: two-pass LDS-binned counting sort ----------------
// pass 0: coarse bucket histogram (LDS-binned, ~77k global atomics total)
__global__ __launch_bounds__(256) void k_cb_hist(const int* __restrict__ dst,
                                                 int* __restrict__ cb){
  __shared__ int h[NB];
  for (int i = threadIdx.x; i < NB; i += 256) h[i] = 0;
  __syncthreads();
  int e0 = blockIdx.x * 8192;
  #pragma unroll 4
  for (int j = 0; j < 32; j++){
    int e = e0 + j * 256 + threadIdx.x;
    if (e < NE) atomicAdd(&h[dst[e] >> 8], 1);
  }
  __syncthreads();
  for (int i = threadIdx.x; i < NB; i += 256)
    if (h[i]) atomicAdd(&cb[i], h[i]);
}

// bucket base scan + init reservation cursors
__global__ void k_cb_scan(const int* __restrict__ cb, int* __restrict__ cbo,
                          int* __restrict__ curB){
  if (threadIdx.x == 0 && blockIdx.x == 0){
    int a = 0;
    for (int i = 0; i < NB; i++){ cbo[i] = a; curB[i] = a; a += cb[i]; }
    cbo[NB] = a;
  }
}

// pass 1: partition edges into bucket-contiguous regions, LDS-staged so global
// writes are contiguous runs (kills the 16x scatter write amplification)
__global__ __launch_bounds__(256) void k_part(const int* __restrict__ src,
                                              const int* __restrict__ dst,
                                              int* __restrict__ curB,
                                              int2* __restrict__ part){
  __shared__ int hist[NB], scn[NB], cur[NB], base[NB];
  __shared__ int2 stage[4096];
  const int tid = threadIdx.x;
  const int e0 = blockIdx.x * 4096;
  const int cnt = min(4096, NE - e0);
  for (int i = tid; i < NB; i += 256) hist[i] = 0;
  __syncthreads();
  int2 ed[16];
  #pragma unroll
  for (int j = 0; j < 16; j++){
    int e = e0 + j * 256 + tid;
    if (e < NE){
      ed[j].x = src[e]; ed[j].y = dst[e];
      atomicAdd(&hist[ed[j].y >> 8], 1);
    }
  }
  __syncthreads();
  // reserve global chunk per bucket; serial exclusive scan (per-wg parallel)
  for (int i = tid; i < NB; i += 256)
    base[i] = hist[i] ? atomicAdd(&curB[i], hist[i]) : 0;
  if (tid == 0){
    int a = 0;
    for (int i = 0; i < NB; i++){ scn[i] = a; cur[i] = a; a += hist[i]; }
  }
  __syncthreads();
  #pragma unroll
  for (int j = 0; j < 16; j++){
    int e = e0 + j * 256 + tid;
    if (e < NE){
      int slot = atomicAdd(&cur[ed[j].y >> 8], 1);
      stage[slot] = ed[j];
    }
  }
  __syncthreads();
  for (int i = tid; i < cnt; i += 256){
    int2 p = stage[i];
    int b = p.y >> 8;
    part[base[b] + (i - scn[b])] = p;
  }
}

// pass 2: one wg per bucket: per-node histogram+scan in LDS -> rp, then scatter
// src ids into the bucket's contiguous esrc region (single-wg locality)
__global__ __launch_bounds__(256) void k_bsort(const int2* __restrict__ part,
                                               const int* __restrict__ cbo,
                                               int* __restrict__ rp,
                                               int* __restrict__ esrc){
  __shared__ int cnt[256], sc[256], cur[256];
  const int tid = threadIdx.x;
  const int b = blockIdx.x;
  const int lo = cbo[b], hi = cbo[b + 1];
  cnt[tid] = 0;
  __syncthreads();
  for (int i = lo + tid; i < hi; i += 256)
    atomicAdd(&cnt[part[i].y & 255], 1);
  __syncthreads();
  // exclusive scan of 256 counters
  sc[tid] = cnt[tid];
  __syncthreads();
  #pragma unroll
  for (int off = 1; off < 256; off <<= 1){
    int t = (tid >= off) ? sc[tid - off] : 0;
    __syncthreads();
    sc[tid] += t;
    __syncthreads();
  }
  int ex = sc[tid] - cnt[tid];
  int n = (b << 8) + tid;
  if (n < NN) rp[n] = lo + ex;
  if (b == NB - 1 && tid == 0) rp[NN] = hi;
  cur[tid] = lo + ex;
  __syncthreads();
  for (int i = lo + tid; i < hi; i += 256){
    int2 p = part[i];
    int pos = atomicAdd(&cur[p.y & 255], 1);
    esrc[pos] = p.x;
  }
}

// ---------------- segment-max aggregation (one wave per node) ----------------
// messages are post-ReLU (>=0), so init 0 reproduces where(isfinite(max), max, 0).
// Unroll x8 with batched loads; tail slots clamp to hi-1 (dup rows harmless).
__global__ void k_agg(const u16* __restrict__ hp, const int* __restrict__ rp,
                      const int* __restrict__ esrc, u16* __restrict__ agg){
  int node = blockIdx.x * 4 + (threadIdx.x >> 6);
  if (node >= NN) return;
  int lane = threadIdx.x & 63;
  int lo = rp[node], hi = rp[node + 1];
  float m0 = 0.f, m1 = 0.f;
  for (int i = lo; i < hi; i += 8){
    int s[8];
    #pragma unroll
    for (int j = 0; j < 8; j++){
      int ii = i + j; if (ii >= hi) ii = hi - 1;
      s[j] = esrc[ii];
    }
    u32 v[8];
    #pragma unroll
    for (int j = 0; j < 8; j++)
      v[j] = *(const u32*)&hp[(size_t)s[j] * 128 + lane * 2];
    #pragma unroll
    for (int j = 0; j < 8; j++){
      m0 = fmaxf(m0, __uint_as_float(v[j] << 16));
      m1 = fmaxf(m1, __uint_as_float(v[j] & 0xffff0000u));
    }
  }
  u32 o = (u32)f2b(m0) | ((u32)f2b(m1) << 16);
  *(u32*)&agg[(size_t)node * 128 + lane * 2] = o;
}

// ---------------- bf16 MFMA GEMM: out = [A1|A2] @ Wt^T + bias (opt relu) -----
// Wt is pre-transposed bf16 [NOUT][K]. A rows are [N][128] (f32 or bf16).
// 16x16x32 MFMA; lane frag A: row=l&15, k=(l>>4)*8+i ; B: k=(l>>4)*8+i, col=l&15
// C/D: col=l&15, row=(l>>4)*4+reg  (m89-verified).
template<int K, int NOUT, int NOUTR, int BM, int NT,
         bool A1F32, bool HASA2, bool RELU, bool OUTF32>
__global__ __launch_bounds__(NT)
void k_gemm(const void* __restrict__ A1p, const u16* __restrict__ A2,
            const u16* __restrict__ Wt, const float* __restrict__ bias,
            void* __restrict__ outp)
{
  constexpr int KSTEP = 64;
  constexpr int KP = KSTEP + 8;     // 72 elems = 144 B rows (16B-aligned, 2-way banks)
  constexpr int NTI = NOUT / 16;
  __shared__ u16 A_lds[BM * KP];
  __shared__ u16 W_lds[NOUT * KP];
  const int tid  = threadIdx.x;
  const int row0 = blockIdx.x * BM;
  const int wave = tid >> 6, lane = tid & 63;
  const int koff = (lane >> 4) * 8;
  const u16* Ar = &A_lds[(wave * 16 + (lane & 15)) * KP];

  f32x4 acc[NTI] = {};

  #pragma unroll
  for (int k0 = 0; k0 < K; k0 += KSTEP){
    if (k0) __syncthreads();
    // stage W chunk [NOUT][64]
    for (int c = tid; c < NOUT * 8; c += NT){
      int n = c >> 3, kc = c & 7;
      *(uint4*)&W_lds[n * KP + kc * 8] = *(const uint4*)&Wt[n * K + k0 + kc * 8];
    }
    // stage A chunk [BM][64]
    if (A1F32 && k0 < 128){
      const float* A = (const float*)A1p;
      for (int c = tid; c < BM * 16; c += NT){
        int rl = c >> 4, kc = c & 15;
        int gr = row0 + rl;
        float4 v = make_float4(0.f, 0.f, 0.f, 0.f);
        if (gr < NN) v = *(const float4*)&A[(size_t)gr * 128 + k0 + kc * 4];
        ushort4 o; o.x = f2b(v.x); o.y = f2b(v.y); o.z = f2b(v.z); o.w = f2b(v.w);
        *(ushort4*)&A_lds[rl * KP + kc * 4] = o;
      }
    } else {
      const u16* A = (HASA2 && k0 >= 128) ? A2 : (const u16*)A1p;
      int cb = (HASA2 && k0 >= 128) ? (k0 - 128) : k0;
      for (int c = tid; c < BM * 8; c += NT){
        int rl = c >> 3, kc = c & 7;
        int gr = row0 + rl;
        uint4 v = make_uint4(0, 0, 0, 0);
        if (gr < NN) v = *(const uint4*)&A[(size_t)gr * 128 + cb + kc * 8];
        *(uint4*)&A_lds[rl * KP + kc * 8] = v;
      }
    }
    __syncthreads();

    bf16x8 af0 = *(const bf16x8*)&Ar[koff];
    bf16x8 af1 = *(const bf16x8*)&Ar[32 + koff];
    #pragma unroll
    for (int nt = 0; nt < NTI; nt++){
      const u16* Wr = &W_lds[(nt * 16 + (lane & 15)) * KP];
      bf16x8 b0 = *(const bf16x8*)&Wr[koff];
      bf16x8 b1 = *(const bf16x8*)&Wr[32 + koff];
      acc[nt] = __builtin_amdgcn_mfma_f32_16x16x32_bf16(af0, b0, acc[nt], 0, 0, 0);
      acc[nt] = __builtin_amdgcn_mfma_f32_16x16x32_bf16(af1, b1, acc[nt], 0, 0, 0);
    }
  }

  const int colb = lane & 15;
  const int rowl = wave * 16 + ((lane >> 4) << 2);
  #pragma unroll
  for (int nt = 0; nt < NTI; nt++){
    int col = nt * 16 + colb;
    if (col >= NOUTR) continue;
    float bv = bias[col];
    #pragma unroll
    for (int r = 0; r < 4; r++){
      int gr = row0 + rowl + r;
      if (gr >= NN) continue;
      float v = acc[nt][r] + bv;
      if (RELU) v = fmaxf(v, 0.f);
      if (OUTF32) ((float*)outp)[(size_t)gr * NOUTR + col] = v;
      else        ((u16*)outp)[(size_t)gr * NOUTR + col] = f2b(v);
    }
  }
}

// ---------------- host launch ----------------
extern "C" void kernel_launch(void* const* d_in, const int* in_sizes, int n_in,
                              void* d_out, int out_size, void* d_ws, size_t ws_size,
                              hipStream_t stream){
  const float* x   = (const float*)d_in[0];
  const int*   src = (const int*)d_in[1];
  const int*   dst = (const int*)d_in[2];
  const float* Wp1 = (const float*)d_in[3];
  const float* bp1 = (const float*)d_in[4];
  const float* Ws1 = (const float*)d_in[5];
  const float* Wn1 = (const float*)d_in[6];
  const float* b1  = (const float*)d_in[7];
  const float* Wp2 = (const float*)d_in[8];
  const float* bp2 = (const float*)d_in[9];
  const float* Ws2 = (const float*)d_in[10];
  const float* Wn2 = (const float*)d_in[11];
  const float* b2  = (const float*)d_in[12];

  char* ws = (char*)d_ws;
  u16* wpT1 = (u16*)(ws + 0);            // 128x128 bf16
  u16* wc1T = (u16*)(ws + 32768);        // 128x256 bf16
  u16* wpT2 = (u16*)(ws + 98304);        // 128x128 bf16
  u16* wc2T = (u16*)(ws + 131072);       // 48x256 bf16 (cols 40..47 zero)
  int* cb   = (int*)(ws + 155648);       // NB bucket counts
  int* cbo  = (int*)(ws + 157696);       // NB+1 bucket offsets
  int* curB = (int*)(ws + 159744);       // NB reservation cursors
  int* rp   = (int*)(ws + 161792);       // N+1 row pointers
  int2* part= (int2*)(ws + 561920);      // E pairs, bucket-grouped (12.8 MB)
  u16* h    = (u16*)(ws + 561920);       // N x 128 bf16 (aliases part; part dead first)
  int* esrc = (int*)(ws + 26161920);     // E src ids sorted by dst (6.4 MB)
  u16* hp   = (u16*)(ws + 32561920);     // N x 128 bf16
  u16* agg  = (u16*)(ws + 58161920);     // N x 128 bf16

  hipMemsetAsync(cb, 0, NB * sizeof(int), stream);
  k_prep<<<128, 256, 0, stream>>>(Wp1, Ws1, Wn1, Wp2, Ws2, Wn2, wpT1, wc1T, wpT2, wc2T);
  k_cb_hist<<<(NE + 8191) / 8192, 256, 0, stream>>>(dst, cb);
  k_cb_scan<<<1, 64, 0, stream>>>(cb, cbo, curB);
  k_part<<<(NE + 4095) / 4096, 256, 0, stream>>>(src, dst, curB, part);
  k_bsort<<<NB, 256, 0, stream>>>(part, cbo, rp, esrc);

  // layer 1
  k_gemm<128,128,128, 64,256, true ,false,true ,false>
      <<<(NN + 63) / 64, 256, 0, stream>>>(x, nullptr, wpT1, bp1, hp);
  k_agg<<<(NN + 3) / 4, 256, 0, stream>>>(hp, rp, esrc, agg);
  k_gemm<256,128,128,128,512, true ,true ,true ,false>
      <<<(NN + 127) / 128, 512, 0, stream>>>(x, agg, wc1T, b1, h);
  // layer 2
  k_gemm<128,128,128, 64,256, false,false,true ,false>
      <<<(NN + 63) / 64, 256, 0, stream>>>(h, nullptr, wpT2, bp2, hp);
  k_agg<<<(NN + 3) / 4, 256, 0, stream>>>(hp, rp, esrc, agg);
  k_gemm<256, 48, 40,128,512, false,true ,false,true >
      <<<(NN + 127) / 128, 512, 0, stream>>>(h, agg, wc2T, b2, d_out);
}